// Round 20
// baseline (99.412 us; speedup 1.0000x reference)
//
#include <hip/hip_runtime.h>

// SNN classifier: T=500, B=256, 96 -> 64 -> 80, leaky (subtract reset).
// f32 BLAS-order arithmetic replicated exactly -> outputs bitwise-identical
// to the passing round-2..19 kernels.
//
// Round-20: R19 banked the mask architecture (K3 ~6us, K2 fixed). K1 (45us)
// is now half the runtime. Model: T = 51/P + 156/waves, P*waves capped by
// LDS. This round breaks the cap: P=4 WITH 8 waves/CU via k-chunked
// double-buffered x staging (4 chunks of 24k, 24.6KB/buf x2 + full W1 =
// 72KB -> 2 blocks/CU). W-broadcasts halve vs R16 while keeping its
// latency hiding. Stage-next placed before compute (loads hoist over the
// 512-FMA block); ONE barrier per chunk (hidden by the co-resident block).
// No W restage (R14 bomb avoided). k ascends across chunks -> bit-identical.
// K2/K3/K4 = R19 verbatim (single-variable change).
// Fallback if regression: R16 K1, declare plateau.

#define T_STEPS 500
#define BATCH   256
#define N_IN    96
#define N_HID   64
#define N_OUT   80
#define CH      50    // chunk size in K2/K4 (500 = 10*50)
#define MASK_OFF 8192000  // float offset of mask region inside outs

// ---------------- K1: cur1 = x @ W1 + b1 ----------------
// grid 125*4, block 256 (4 waves = 4 h-quarters). Block = (t-quad, 64-b).
// LDS (one array, 72KB): xs buf0 @0, xs buf1 @6144 (each 4t*64b*24k),
// W1 @12288 ([96][64]). Epilogue reuses all of it for 4 transpose tiles.
__global__ __launch_bounds__(256) void k1_cur1(
    const float* __restrict__ x,   // (T,B,96)
    const float* __restrict__ W1,  // (96,64)
    const float* __restrict__ b1,  // (64)
    float* __restrict__ cur1)      // (T,B,64) region inside outs
{
    const int tq   = blockIdx.x >> 2;        // 0..124
    const int b0   = (blockIdx.x & 3) << 6;
    const int t0   = tq * 4;
    const int lane = threadIdx.x & 63;       // = local b
    const int w    = threadIdx.x >> 6;       // wave id = h-quarter
    const int o0   = w << 4;

    __shared__ float sm[18432];              // 72 KB
    const int XS0 = 0, XS1 = 6144, WS = 12288;

    // ---- stage W1 (once) + x chunk 0 into buf0
    {
        const float4* __restrict__ srcw = reinterpret_cast<const float4*>(W1);
        #pragma unroll
        for (int ii = 0; ii < 6; ++ii) {
            const int i = ii * 256 + threadIdx.x;
            *reinterpret_cast<float4*>(&sm[WS + i * 4]) = srcw[i];
        }
        #pragma unroll
        for (int ii = 0; ii < 6; ++ii) {
            const int i   = ii * 256 + threadIdx.x;   // 1536 granules
            const int row = i / 6, g = i % 6;         // row = p*64+bb
            const int p   = row >> 6, bb = row & 63;
            const float4 v = *reinterpret_cast<const float4*>(
                x + ((size_t)(t0 + p) * BATCH + b0 + bb) * N_IN + g * 4);
            *reinterpret_cast<float4*>(&sm[XS0 + row * 24 + g * 4]) = v;
        }
    }
    __syncthreads();

    float acc[4][16];
    #pragma unroll
    for (int p = 0; p < 4; ++p)
        #pragma unroll
        for (int o = 0; o < 16; ++o) acc[p][o] = 0.0f;

    #pragma unroll 1
    for (int c = 0; c < 4; ++c) {            // four 24-k chunks, k ascending
        const int rd = (c & 1) ? XS1 : XS0;
        const int wr_ = (c & 1) ? XS0 : XS1;

        // ---- stage chunk c+1 (source-first: loads hoist above the FMAs)
        if (c < 3) {
            #pragma unroll
            for (int ii = 0; ii < 6; ++ii) {
                const int i   = ii * 256 + threadIdx.x;
                const int row = i / 6, g = i % 6;
                const int p   = row >> 6, bb = row & 63;
                const float4 v = *reinterpret_cast<const float4*>(
                    x + ((size_t)(t0 + p) * BATCH + b0 + bb) * N_IN
                      + (c + 1) * 24 + g * 4);
                *reinterpret_cast<float4*>(&sm[wr_ + row * 24 + g * 4]) = v;
            }
        }

        // ---- compute chunk c (DS-only inner loop)
        #pragma unroll
        for (int kg = 0; kg < 6; ++kg) {
            float4 xv0 = *reinterpret_cast<const float4*>(&sm[rd + (0 * 64 + lane) * 24 + kg * 4]);
            float4 xv1 = *reinterpret_cast<const float4*>(&sm[rd + (1 * 64 + lane) * 24 + kg * 4]);
            float4 xv2 = *reinterpret_cast<const float4*>(&sm[rd + (2 * 64 + lane) * 24 + kg * 4]);
            float4 xv3 = *reinterpret_cast<const float4*>(&sm[rd + (3 * 64 + lane) * 24 + kg * 4]);
            const float xq[4][4] = {{xv0.x, xv0.y, xv0.z, xv0.w},
                                    {xv1.x, xv1.y, xv1.z, xv1.w},
                                    {xv2.x, xv2.y, xv2.z, xv2.w},
                                    {xv3.x, xv3.y, xv3.z, xv3.w}};
            #pragma unroll
            for (int jj = 0; jj < 4; ++jj) {
                const int k = c * 24 + kg * 4 + jj;
                const float4* __restrict__ wvp =            // LDS broadcast
                    reinterpret_cast<const float4*>(&sm[WS + k * 64 + o0]);
                const float4 w0 = wvp[0], w1 = wvp[1], w2 = wvp[2], w3 = wvp[3];
                const float wv[16] = {w0.x, w0.y, w0.z, w0.w,
                                      w1.x, w1.y, w1.z, w1.w,
                                      w2.x, w2.y, w2.z, w2.w,
                                      w3.x, w3.y, w3.z, w3.w};
                #pragma unroll
                for (int p = 0; p < 4; ++p) {
                    const float xs = xq[p][jj];
                    #pragma unroll
                    for (int o = 0; o < 16; ++o)
                        acc[p][o] = __fmaf_rn(xs, wv[o], acc[p][o]);
                }
            }
        }
        __syncthreads();   // buf[c+1] staged AND buf-reads of this chunk done
    }

    // ---- bias, transpose 4 t-tiles via LDS (clobbers everything), linear stores
    #pragma unroll
    for (int p = 0; p < 4; ++p) {
        #pragma unroll
        for (int o4 = 0; o4 < 4; ++o4) {
            float4 v;
            v.x = __fadd_rn(acc[p][o4 * 4 + 0], b1[o0 + o4 * 4 + 0]);
            v.y = __fadd_rn(acc[p][o4 * 4 + 1], b1[o0 + o4 * 4 + 1]);
            v.z = __fadd_rn(acc[p][o4 * 4 + 2], b1[o0 + o4 * 4 + 2]);
            v.w = __fadd_rn(acc[p][o4 * 4 + 3], b1[o0 + o4 * 4 + 3]);
            *reinterpret_cast<float4*>(&sm[p * 4352 + lane * 68 + o0 + o4 * 4]) = v;
        }
    }
    __syncthreads();
    #pragma unroll
    for (int p = 0; p < 4; ++p) {
        float4* __restrict__ dst = reinterpret_cast<float4*>(
            cur1 + ((size_t)(t0 + p) * BATCH + b0) * N_HID);
        #pragma unroll
        for (int ii = 0; ii < 4; ++ii) {
            const int i = ii * 256 + threadIdx.x;
            const int row = i / 16, g = i % 16;
            dst[i] = *reinterpret_cast<const float4*>(&sm[p * 4352 + row * 68 + g * 4]);
        }
    }
}

// ---------------- K2: layer-1 recurrence -> BITPACKED spikes ---- (R19 verbatim)
__global__ __launch_bounds__(64) void k2_rec1(
    const float* __restrict__ cs,            // cur1 in outs
    unsigned long long* __restrict__ masks)  // (T,B) u64, in outs tail
{
    const int b = blockIdx.x;
    const int h = threadIdx.x;
    const size_t str  = (size_t)BATCH * N_HID;
    const size_t base = (size_t)b * N_HID + h;

    float A[CH], Bv[CH];
    #pragma unroll
    for (int i = 0; i < CH; ++i) A[i] = cs[(size_t)i * str + base];

    float mem = 0.f, s = 0.f;
    unsigned mlo = 0u, mhi = 0u;     // lane h holds mask of step chunk*50+h
    for (int cp = 0; cp < 5; ++cp) {            // 10 chunks, processed in pairs
        const int c0 = 2 * cp;
        #pragma unroll
        for (int i = 0; i < CH; ++i)            // prefetch chunk c0+1
            Bv[i] = cs[(size_t)((c0 + 1) * CH + i) * str + base];
        #pragma unroll
        for (int i = 0; i < CH; ++i) {          // compute chunk c0 from A
            const float m = __fsub_rn(__fadd_rn(__fmul_rn(0.95f, mem), A[i]), s);
            mem = m; s = (m > 1.0f) ? 1.0f : 0.0f;
            const unsigned long long bal = __ballot(m > 1.0f);
            mlo = (h == i) ? (unsigned)bal : mlo;
            mhi = (h == i) ? (unsigned)(bal >> 32) : mhi;
        }
        if (h < CH)                              // one 50-lane store per chunk
            masks[(size_t)(c0 * CH + h) * BATCH + b] =
                ((unsigned long long)mhi << 32) | mlo;
        if (cp < 4) {
            #pragma unroll
            for (int i = 0; i < CH; ++i)        // prefetch chunk c0+2
                A[i] = cs[(size_t)((c0 + 2) * CH + i) * str + base];
        }
        #pragma unroll
        for (int i = 0; i < CH; ++i) {          // compute chunk c0+1 from Bv
            const float m = __fsub_rn(__fadd_rn(__fmul_rn(0.95f, mem), Bv[i]), s);
            mem = m; s = (m > 1.0f) ? 1.0f : 0.0f;
            const unsigned long long bal = __ballot(m > 1.0f);
            mlo = (h == i) ? (unsigned)bal : mlo;
            mhi = (h == i) ? (unsigned)(bal >> 32) : mhi;
        }
        if (h < CH)
            masks[(size_t)((c0 + 1) * CH + h) * BATCH + b] =
                ((unsigned long long)mhi << 32) | mlo;
    }
}

// ---------------- K3: cur2 = spk @ W2 + b2 (mask-driven, P=4) ---- (R19 verbatim)
__global__ __launch_bounds__(256) void k3_cur2(
    const unsigned long long* __restrict__ masks,  // (T,B)
    const float* __restrict__ W2,   // (64,80)
    const float* __restrict__ b2,   // (80)
    float* __restrict__ cur2)       // (T,B,80) = outm region
{
    const int tq   = blockIdx.x >> 2;        // 0..124
    const int b0   = (blockIdx.x & 3) << 6;
    const int t0   = tq * 4;
    const int lane = threadIdx.x & 63;       // = local b
    const int w    = threadIdx.x >> 6;       // wave id
    const int o0   = w * 20;

    __shared__ float ws[64 * 80];            // 20.5 KB, W2 [k][o]

    {
        const float4* __restrict__ srcw = reinterpret_cast<const float4*>(W2);
        #pragma unroll
        for (int ii = 0; ii < 5; ++ii) {
            const int i = ii * 256 + threadIdx.x;
            *reinterpret_cast<float4*>(&ws[i * 4]) = srcw[i];
        }
    }

    unsigned long long mk0, mk1, mk2, mk3;   // per-lane spike masks (4 t's)
    mk0 = masks[(size_t)(t0 + 0) * BATCH + b0 + lane];
    mk1 = masks[(size_t)(t0 + 1) * BATCH + b0 + lane];
    mk2 = masks[(size_t)(t0 + 2) * BATCH + b0 + lane];
    mk3 = masks[(size_t)(t0 + 3) * BATCH + b0 + lane];
    __syncthreads();

    float acc0[20], acc1[20], acc2[20], acc3[20];
    #pragma unroll
    for (int o = 0; o < 20; ++o) {
        acc0[o] = 0.0f; acc1[o] = 0.0f; acc2[o] = 0.0f; acc3[o] = 0.0f;
    }

    #pragma unroll 2
    for (int kg = 0; kg < 16; ++kg) {
        #pragma unroll
        for (int jj = 0; jj < 4; ++jj) {
            const int k = kg * 4 + jj;
            const float4* __restrict__ wr =                 // LDS broadcast
                reinterpret_cast<const float4*>(&ws[k * 80 + o0]);
            const float4 w0 = wr[0], w1 = wr[1], w2 = wr[2], w3 = wr[3], w4 = wr[4];
            const float wv[20] = {w0.x, w0.y, w0.z, w0.w,
                                  w1.x, w1.y, w1.z, w1.w,
                                  w2.x, w2.y, w2.z, w2.w,
                                  w3.x, w3.y, w3.z, w3.w,
                                  w4.x, w4.y, w4.z, w4.w};
            // sf in {0.0f, 1.0f}: FMA bitwise == FMA with stored spike float
            const float s0 = (float)((mk0 >> k) & 1ULL);
            const float s1 = (float)((mk1 >> k) & 1ULL);
            const float s2 = (float)((mk2 >> k) & 1ULL);
            const float s3 = (float)((mk3 >> k) & 1ULL);
            #pragma unroll
            for (int o = 0; o < 20; ++o) {
                acc0[o] = __fmaf_rn(s0, wv[o], acc0[o]);
                acc1[o] = __fmaf_rn(s1, wv[o], acc1[o]);
                acc2[o] = __fmaf_rn(s2, wv[o], acc2[o]);
                acc3[o] = __fmaf_rn(s3, wv[o], acc3[o]);
            }
        }
    }

    #pragma unroll
    for (int o4 = 0; o4 < 5; ++o4) {
        const float bb0 = b2[o0 + o4 * 4 + 0], bb1 = b2[o0 + o4 * 4 + 1];
        const float bb2 = b2[o0 + o4 * 4 + 2], bb3 = b2[o0 + o4 * 4 + 3];
        float4 v;
        float* d;
        v.x = __fadd_rn(acc0[o4 * 4 + 0], bb0);
        v.y = __fadd_rn(acc0[o4 * 4 + 1], bb1);
        v.z = __fadd_rn(acc0[o4 * 4 + 2], bb2);
        v.w = __fadd_rn(acc0[o4 * 4 + 3], bb3);
        d = cur2 + ((size_t)(t0 + 0) * BATCH + b0 + lane) * N_OUT + o0;
        reinterpret_cast<float4*>(d)[o4] = v;
        v.x = __fadd_rn(acc1[o4 * 4 + 0], bb0);
        v.y = __fadd_rn(acc1[o4 * 4 + 1], bb1);
        v.z = __fadd_rn(acc1[o4 * 4 + 2], bb2);
        v.w = __fadd_rn(acc1[o4 * 4 + 3], bb3);
        d = cur2 + ((size_t)(t0 + 1) * BATCH + b0 + lane) * N_OUT + o0;
        reinterpret_cast<float4*>(d)[o4] = v;
        v.x = __fadd_rn(acc2[o4 * 4 + 0], bb0);
        v.y = __fadd_rn(acc2[o4 * 4 + 1], bb1);
        v.z = __fadd_rn(acc2[o4 * 4 + 2], bb2);
        v.w = __fadd_rn(acc2[o4 * 4 + 3], bb3);
        d = cur2 + ((size_t)(t0 + 2) * BATCH + b0 + lane) * N_OUT + o0;
        reinterpret_cast<float4*>(d)[o4] = v;
        v.x = __fadd_rn(acc3[o4 * 4 + 0], bb0);
        v.y = __fadd_rn(acc3[o4 * 4 + 1], bb1);
        v.z = __fadd_rn(acc3[o4 * 4 + 2], bb2);
        v.w = __fadd_rn(acc3[o4 * 4 + 3], bb3);
        d = cur2 + ((size_t)(t0 + 3) * BATCH + b0 + lane) * N_OUT + o0;
        reinterpret_cast<float4*>(d)[o4] = v;
    }
}

// ---------------- K4: layer-2 recurrence (cur2 in outm -> spk/mem finals) ----------------
__global__ __launch_bounds__(80) void k4_rec2(float* cm, float* os)
{
    const int b = blockIdx.x;
    const int o = threadIdx.x;   // 0..79
    const size_t str  = (size_t)BATCH * N_OUT;
    const size_t base = (size_t)b * N_OUT + o;

    float A[CH], Bv[CH];
    #pragma unroll
    for (int i = 0; i < CH; ++i) A[i] = cm[(size_t)i * str + base];

    float mem = 0.f, s = 0.f;
    for (int cp = 0; cp < 5; ++cp) {
        const int c0 = 2 * cp;
        #pragma unroll
        for (int i = 0; i < CH; ++i)
            Bv[i] = cm[(size_t)((c0 + 1) * CH + i) * str + base];
        #pragma unroll
        for (int i = 0; i < CH; ++i) {
            const int t = c0 * CH + i;
            const float m = __fsub_rn(__fadd_rn(__fmul_rn(0.95f, mem), A[i]), s);
            mem = m; s = (m > 1.0f) ? 1.0f : 0.0f;
            os[(size_t)t * str + base] = s;
            cm[(size_t)t * str + base] = m;
        }
        if (cp < 4) {
            #pragma unroll
            for (int i = 0; i < CH; ++i)
                A[i] = cm[(size_t)((c0 + 2) * CH + i) * str + base];
        }
        #pragma unroll
        for (int i = 0; i < CH; ++i) {
            const int t = (c0 + 1) * CH + i;
            const float m = __fsub_rn(__fadd_rn(__fmul_rn(0.95f, mem), Bv[i]), s);
            mem = m; s = (m > 1.0f) ? 1.0f : 0.0f;
            os[(size_t)t * str + base] = s;
            cm[(size_t)t * str + base] = m;
        }
    }
}

extern "C" void kernel_launch(void* const* d_in, const int* in_sizes, int n_in,
                              void* d_out, int out_size, void* d_ws, size_t ws_size,
                              hipStream_t stream) {
    const float* x  = (const float*)d_in[0];
    const float* W1 = (const float*)d_in[1];
    const float* b1 = (const float*)d_in[2];
    const float* W2 = (const float*)d_in[3];
    const float* b2 = (const float*)d_in[4];
    float* outs = (float*)d_out;                                   // (T,B,80) spikes
    float* outm = outs + (size_t)T_STEPS * BATCH * N_OUT;          // (T,B,80) mem
    unsigned long long* masks =
        (unsigned long long*)(outs + MASK_OFF);                    // 1MB in outs tail

    k1_cur1<<<125 * 4, 256, 0, stream>>>(x, W1, b1, outs);         // cur1 -> outs
    k2_rec1<<<BATCH, 64, 0, stream>>>(outs, masks);                // masks -> outs tail
    k3_cur2<<<125 * 4, 256, 0, stream>>>(masks, W2, b2, outm);     // cur2 -> outm
    k4_rec2<<<BATCH, 80, 0, stream>>>(outm, outs);                 // finals in place
}